// Round 1
// baseline (45.631 us; speedup 1.0000x reference)
//
#include <hip/hip_runtime.h>

// out[b,t,h,d] = cos(x[b,t,h,d] + sum_j theta[h,j])
// B=64, T=8192, H=8, HD=8 -> 33,554,432 f32 elements. Memory-bound streaming op.

__global__ __launch_bounds__(256) void mhaq_cos_kernel(
    const float* __restrict__ x,
    const float* __restrict__ theta,
    float* __restrict__ out,
    long long n4)
{
    // Per-head total phase: phase[h] = sum_{j<8} theta[h*8+j]. theta is 64 floats,
    // L1-resident; compute once per block into LDS.
    __shared__ float s_phase[8];
    if (threadIdx.x < 8) {
        float p = 0.0f;
        #pragma unroll
        for (int j = 0; j < 8; ++j) p += theta[threadIdx.x * 8 + j];
        s_phase[threadIdx.x] = p;
    }
    __syncthreads();

    const float4* __restrict__ x4 = reinterpret_cast<const float4*>(x);
    float4* __restrict__ o4 = reinterpret_cast<float4*>(out);

    const float inv2pi = 0.15915494309189535f; // 1/(2*pi) — inline constant on gfx950

    const long long stride = (long long)gridDim.x * blockDim.x;
    for (long long i = (long long)blockIdx.x * blockDim.x + threadIdx.x; i < n4; i += stride) {
        float4 v = x4[i];
        // flat element index = 4*i; column within the 64-wide row = (4*i) & 63;
        // head = column >> 3  ==>  h = (i & 15) >> 1. A 4-aligned float4 never
        // straddles a head boundary (HD=8).
        int h = (int)((i & 15) >> 1);
        float ph = s_phase[h];

        float4 r;
        // cos(a) with a in radians: v_cos_f32 takes revolutions, reduce with v_fract.
        // fract(x) = x - floor(x) in [0,1); cos is 2π-periodic so this is exact math.
        r.x = __builtin_amdgcn_cosf(__builtin_amdgcn_fractf((v.x + ph) * inv2pi));
        r.y = __builtin_amdgcn_cosf(__builtin_amdgcn_fractf((v.y + ph) * inv2pi));
        r.z = __builtin_amdgcn_cosf(__builtin_amdgcn_fractf((v.z + ph) * inv2pi));
        r.w = __builtin_amdgcn_cosf(__builtin_amdgcn_fractf((v.w + ph) * inv2pi));

        o4[i] = r;
    }
}

extern "C" void kernel_launch(void* const* d_in, const int* in_sizes, int n_in,
                              void* d_out, int out_size, void* d_ws, size_t ws_size,
                              hipStream_t stream) {
    const float* x     = (const float*)d_in[0];   // [B,T,H*HD] f32
    const float* theta = (const float*)d_in[1];   // [H,HD] f32
    float* out         = (float*)d_out;           // [B,T,H*HD] f32

    long long n  = (long long)out_size;           // 33,554,432 (divisible by 4)
    long long n4 = n >> 2;

    const int block = 256;
    const int grid  = 2048; // 256 CUs x 8 blocks/CU; grid-stride covers the rest

    mhaq_cos_kernel<<<grid, block, 0, stream>>>(x, theta, out, n4);
}